// Round 4
// baseline (193.849 us; speedup 1.0000x reference)
//
#include <hip/hip_runtime.h>

#define HEADS 8
#define DIM 32
#define DEGREE 16
#define NEG_SLOPE 0.2f

// bf16 <-> fp32 bit tricks (RNE down-convert; exact widening up-convert).
__device__ __forceinline__ unsigned short f2bf(float f) {
  unsigned u = __float_as_uint(f);
  unsigned r = (u + 0x7fffu + ((u >> 16) & 1u)) >> 16;
  return (unsigned short)r;
}
__device__ __forceinline__ float bf2f(unsigned short b) {
  return __uint_as_float(((unsigned)b) << 16);
}

// Kernel 1: float4 per thread. Computes el/er via 8-lane shuffle reduction,
// writes them TRANSPOSED ([h][N] — so each head's logit table is a contiguous
// 200 KB window, L2-resident on every XCD), and writes a bf16 copy of feat.
template <bool WRITE_BF16>
__global__ __launch_bounds__(256) void elr_kernel(
    const float4* __restrict__ feat4,
    const float4* __restrict__ attn_l4,
    const float4* __restrict__ attn_r4,
    float* __restrict__ elT, float* __restrict__ erT,
    ushort4* __restrict__ featb, int total4, int N) {
  int t = blockIdx.x * 256 + threadIdx.x;
  if (t >= total4) return;
  float4 v = feat4[t];
  int c4 = t & 63;                       // column/4 within the 256-wide row
  float4 al = attn_l4[c4];
  float4 ar = attn_r4[c4];
  float pl = v.x * al.x + v.y * al.y + v.z * al.z + v.w * al.w;
  float pr = v.x * ar.x + v.y * ar.y + v.z * ar.z + v.w * ar.w;
#pragma unroll
  for (int off = 4; off >= 1; off >>= 1) {
    pl += __shfl_xor(pl, off);
    pr += __shfl_xor(pr, off);
  }
  if ((t & 7) == 0) {
    int n = t >> 6;
    int h = c4 >> 3;
    elT[h * N + n] = pl;
    erT[h * N + n] = pr;
  }
  if (WRITE_BF16) {
    ushort4 b;
    b.x = f2bf(v.x); b.y = f2bf(v.y); b.z = f2bf(v.z); b.w = f2bf(v.w);
    featb[t] = b;
  }
}

// Kernel 2 (sliced): block handles 16 nodes x ONE head; h = blockIdx % 8 so
// (assuming round-robin workgroup->XCD dispatch) each XCD only gathers from
// one head's 3.2 MB sub-table -> fits its private 4 MB L2, killing the 8x
// fetch replication. Correct regardless of the actual XCD mapping.
// Wave = 4 node-groups of 16 lanes.
//  Phase A (per 16-lane group): lane i loads src_i, logit, 16-wide softmax.
//  Phase B: 4 passes; lane (q=(l>>2)&3, c=l&3) loads 16B chunk c of edge
//  j=p*4+q's 64 B head-slice (4 lanes = 1 cache line), accumulates 8 dims.
//  Reduce over q via shfl_xor(4,8); q==0 lanes write 32 B each.
__global__ __launch_bounds__(256) void gat_sliced_kernel(
    const uint4* __restrict__ featb,   // bf16 feat, [n][256] elementwise
    const float* __restrict__ elT,     // [h][N]
    const float* __restrict__ erT,     // [h][N]
    const int* __restrict__ srcIdx,
    const float* __restrict__ bias,
    float* __restrict__ out, int N) {
  int lane = threadIdx.x & 63;
  int wave = threadIdx.x >> 6;
  int h = blockIdx.x & 7;
  int chunk = blockIdx.x >> 3;
  int g = lane >> 4;                   // node-subgroup within wave
  int l16 = lane & 15;
  int n = chunk * 16 + wave * 4 + g;
  bool ok = (n < N);                   // uniform per 16-lane group

  int sidx = 0;
  float w = 0.0f;
  if (ok) {
    sidx = srcIdx[n * DEGREE + l16];
    float e = elT[h * N + sidx] + erT[h * N + n];
    e = e > 0.0f ? e : NEG_SLOPE * e;
    float m = e;
#pragma unroll
    for (int off = 8; off >= 1; off >>= 1) m = fmaxf(m, __shfl_xor(m, off));
    float x = __expf(e - m);
    float s = x;
#pragma unroll
    for (int off = 8; off >= 1; off >>= 1) s += __shfl_xor(s, off);
    w = x / s;
  }

  if (ok) {
    int q = (lane >> 2) & 3;
    int c = lane & 3;
    int base = lane & 48;              // first lane of this 16-group
    float acc[8];
#pragma unroll
    for (int k = 0; k < 8; k++) acc[k] = 0.0f;
#pragma unroll
    for (int p = 0; p < 4; p++) {
      int j = p * 4 + q;
      int sj = __shfl(sidx, base + j);
      float wj = __shfl(w, base + j);
      // byte address: sj*512 + h*64 + c*16 ; uint4 index = that >> 4
      uint4 r = featb[(size_t)sj * 32 + h * 4 + c];
      acc[0] += wj * __uint_as_float(r.x << 16);
      acc[1] += wj * __uint_as_float(r.x & 0xffff0000u);
      acc[2] += wj * __uint_as_float(r.y << 16);
      acc[3] += wj * __uint_as_float(r.y & 0xffff0000u);
      acc[4] += wj * __uint_as_float(r.z << 16);
      acc[5] += wj * __uint_as_float(r.z & 0xffff0000u);
      acc[6] += wj * __uint_as_float(r.w << 16);
      acc[7] += wj * __uint_as_float(r.w & 0xffff0000u);
    }
#pragma unroll
    for (int k = 0; k < 8; k++) {
      acc[k] += __shfl_xor(acc[k], 4);
      acc[k] += __shfl_xor(acc[k], 8);
    }
    if (q == 0) {
      const float4* bias4 = (const float4*)bias;
      int bidx = h * 8 + c * 2;            // float4 index into bias
      float4 b0 = bias4[bidx], b1 = bias4[bidx + 1];
      float4 o0 = make_float4(acc[0] + b0.x, acc[1] + b0.y,
                              acc[2] + b0.z, acc[3] + b0.w);
      float4 o1 = make_float4(acc[4] + b1.x, acc[5] + b1.y,
                              acc[6] + b1.z, acc[7] + b1.w);
      size_t o = (size_t)n * 64 + h * 8 + c * 2;   // float4 index into out
      ((float4*)out)[o] = o0;
      ((float4*)out)[o + 1] = o1;
    }
  }
}

// Fallback (fp32, full-row gather) if ws can't hold the bf16 copy.
__global__ __launch_bounds__(256) void gat_f32_kernel(
    const float4* __restrict__ featv,
    const float* __restrict__ elT,
    const float* __restrict__ erT,
    const int* __restrict__ srcIdx,
    const float* __restrict__ bias,
    float* __restrict__ out, int N) {
  int wave = threadIdx.x >> 6;
  int lane = threadIdx.x & 63;
  int n = blockIdx.x * 4 + wave;
  __shared__ float s_a[4][DEGREE][HEADS + 1];
  bool active = (n < N);
  int sidx = 0;
  if (active) {
    const int* s = srcIdx + n * DEGREE;
    int i = lane & 15;
    int hh = lane >> 4;
    sidx = s[i];
    float e0 = elT[hh * N + sidx]       + erT[hh * N + n];
    float e1 = elT[(hh + 4) * N + sidx] + erT[(hh + 4) * N + n];
    e0 = e0 > 0.0f ? e0 : NEG_SLOPE * e0;
    e1 = e1 > 0.0f ? e1 : NEG_SLOPE * e1;
    float m0 = e0, m1 = e1;
#pragma unroll
    for (int off = 8; off >= 1; off >>= 1) {
      m0 = fmaxf(m0, __shfl_xor(m0, off));
      m1 = fmaxf(m1, __shfl_xor(m1, off));
    }
    float x0 = __expf(e0 - m0), x1 = __expf(e1 - m1);
    float s0 = x0, s1 = x1;
#pragma unroll
    for (int off = 8; off >= 1; off >>= 1) {
      s0 += __shfl_xor(s0, off);
      s1 += __shfl_xor(s1, off);
    }
    s_a[wave][i][hh]     = x0 / s0;
    s_a[wave][i][hh + 4] = x1 / s1;
  }
  __syncthreads();
  if (active) {
    int h = lane >> 3;
    float4 acc = ((const float4*)bias)[lane];
#pragma unroll
    for (int j = 0; j < DEGREE; j++) {
      int sj = __shfl(sidx, j);
      float a = s_a[wave][j][h];
      float4 v = featv[(size_t)sj * 64 + lane];
      acc.x += a * v.x; acc.y += a * v.y; acc.z += a * v.z; acc.w += a * v.w;
    }
    ((float4*)out)[(size_t)n * 64 + lane] = acc;
  }
}

extern "C" void kernel_launch(void* const* d_in, const int* in_sizes, int n_in,
                              void* d_out, int out_size, void* d_ws, size_t ws_size,
                              hipStream_t stream) {
  const float* feat   = (const float*)d_in[0];
  const float* attn_l = (const float*)d_in[1];
  const float* attn_r = (const float*)d_in[2];
  const float* bias   = (const float*)d_in[3];
  const int*   src    = (const int*)d_in[4];
  // d_in[5] (dst) unused: dst == repeat(arange(N), DEG) by construction.
  float* out = (float*)d_out;

  int total = in_sizes[0];               // N * H * D
  int N = total / (HEADS * DIM);
  int total4 = total / 4;

  float* elT = (float*)d_ws;
  float* erT = elT + (size_t)N * HEADS;
  ushort4* featb = (ushort4*)(erT + (size_t)N * HEADS);

  size_t need = (size_t)N * HEADS * 2 * sizeof(float) + (size_t)total * 2;
  bool use_bf16 = (ws_size >= need);

  if (use_bf16) {
    elr_kernel<true><<<(total4 + 255) / 256, 256, 0, stream>>>(
        (const float4*)feat, (const float4*)attn_l, (const float4*)attn_r,
        elT, erT, featb, total4, N);
    int nchunks = (N + 15) / 16;
    gat_sliced_kernel<<<nchunks * 8, 256, 0, stream>>>(
        (const uint4*)featb, elT, erT, src, bias, out, N);
  } else {
    elr_kernel<false><<<(total4 + 255) / 256, 256, 0, stream>>>(
        (const float4*)feat, (const float4*)attn_l, (const float4*)attn_r,
        elT, erT, nullptr, total4, N);
    int nb = (N + 3) / 4;
    gat_f32_kernel<<<nb, 256, 0, stream>>>(
        (const float4*)feat, elT, erT, src, bias, out, N);
  }
}

// Round 5
// 175.825 us; speedup vs baseline: 1.1025x; 1.1025x over previous
//
#include <hip/hip_runtime.h>

#define HEADS 8
#define DIM 32
#define DEGREE 16
#define NEG_SLOPE 0.2f

// bf16 <-> fp32 bit tricks (RNE down-convert; exact widening up-convert).
__device__ __forceinline__ unsigned short f2bf(float f) {
  unsigned u = __float_as_uint(f);
  unsigned r = (u + 0x7fffu + ((u >> 16) & 1u)) >> 16;
  return (unsigned short)r;
}

// Kernel 1: float4 per thread. Computes el/er via 8-lane shuffle reduction,
// writes them TRANSPOSED ([h][N]), and writes a HEAD-MAJOR bf16 copy of feat:
// featbH[h][n][32] — head h's table is a contiguous 3.2 MB stripe, so an XCD
// gathering only head h has a <4 MB L2 working set (lines hold head-h data only).
template <bool WRITE_BF16>
__global__ __launch_bounds__(256) void elr_kernel(
    const float4* __restrict__ feat4,
    const float4* __restrict__ attn_l4,
    const float4* __restrict__ attn_r4,
    float* __restrict__ elT, float* __restrict__ erT,
    ushort4* __restrict__ featbH, int total4, int N) {
  int t = blockIdx.x * 256 + threadIdx.x;
  if (t >= total4) return;
  float4 v = feat4[t];
  int c4 = t & 63;                       // column/4 within the 256-wide row
  float4 al = attn_l4[c4];
  float4 ar = attn_r4[c4];
  float pl = v.x * al.x + v.y * al.y + v.z * al.z + v.w * al.w;
  float pr = v.x * ar.x + v.y * ar.y + v.z * ar.z + v.w * ar.w;
#pragma unroll
  for (int off = 4; off >= 1; off >>= 1) {
    pl += __shfl_xor(pl, off);
    pr += __shfl_xor(pr, off);
  }
  int n = t >> 6;
  int h = c4 >> 3;
  if ((t & 7) == 0) {
    elT[h * N + n] = pl;
    erT[h * N + n] = pr;
  }
  if (WRITE_BF16) {
    ushort4 b;
    b.x = f2bf(v.x); b.y = f2bf(v.y); b.z = f2bf(v.z); b.w = f2bf(v.w);
    int d4 = c4 & 7;                     // float4 chunk within the head slice
    featbH[((size_t)h * N + n) * 8 + d4] = b;
  }
}

// Kernel 2: block = 16 nodes x ONE head; h = blockIdx & 7 so (under round-robin
// workgroup->XCD dispatch) each XCD gathers only from head h's contiguous
// 3.2 MB featbH stripe -> L2-resident, compulsory misses only. Correct
// regardless of the actual mapping (G16) — mapping affects speed only.
//  - src indices staged in LDS once per block (kills 8x reload).
//  - Phase A: 16-lane group per node: logit + 16-wide softmax.
//  - Phase B: lane (q,c) loads 16 B chunk c of edge j=p*4+q's 64 B slice;
//    4 passes; reduce over q via shfl_xor(4,8); q==0 lanes write 32 B.
__global__ __launch_bounds__(256) void gat_hmajor_kernel(
    const uint4* __restrict__ featbH,  // slice (h,n) = 4 uint4 at (h*N+n)*4
    const float* __restrict__ elT,     // [h][N]
    const float* __restrict__ erT,     // [h][N]
    const int* __restrict__ srcIdx,
    const float* __restrict__ bias,
    float* __restrict__ out, int N) {
  int h = blockIdx.x & 7;
  int chunk = blockIdx.x >> 3;
  int tid = threadIdx.x;
  __shared__ int s_src[16][DEGREE];
  {
    int nl = tid >> 4, e = tid & 15;
    int nn = chunk * 16 + nl;
    s_src[nl][e] = (nn < N) ? srcIdx[nn * DEGREE + e] : 0;
  }
  __syncthreads();

  int lane = tid & 63;
  int wave = tid >> 6;
  int g = lane >> 4;                   // node-subgroup within wave
  int l16 = lane & 15;
  int nl = wave * 4 + g;
  int n = chunk * 16 + nl;
  if (n >= N) return;                  // uniform per 16-lane group

  int sidx = s_src[nl][l16];
  float e = elT[h * N + sidx] + erT[h * N + n];
  e = e > 0.0f ? e : NEG_SLOPE * e;
  float m = e;
#pragma unroll
  for (int off = 8; off >= 1; off >>= 1) m = fmaxf(m, __shfl_xor(m, off));
  float x = __expf(e - m);
  float s = x;
#pragma unroll
  for (int off = 8; off >= 1; off >>= 1) s += __shfl_xor(s, off);
  float w = x / s;

  int q = (lane >> 2) & 3;
  int c = lane & 3;
  int base = lane & 48;                // first lane of this 16-group
  float acc[8];
#pragma unroll
  for (int k = 0; k < 8; k++) acc[k] = 0.0f;
#pragma unroll
  for (int p = 0; p < 4; p++) {
    int j = p * 4 + q;
    int sj = __shfl(sidx, base + j);
    float wj = __shfl(w, base + j);
    uint4 r = featbH[((size_t)h * N + sj) * 4 + c];
    acc[0] += wj * __uint_as_float(r.x << 16);
    acc[1] += wj * __uint_as_float(r.x & 0xffff0000u);
    acc[2] += wj * __uint_as_float(r.y << 16);
    acc[3] += wj * __uint_as_float(r.y & 0xffff0000u);
    acc[4] += wj * __uint_as_float(r.z << 16);
    acc[5] += wj * __uint_as_float(r.z & 0xffff0000u);
    acc[6] += wj * __uint_as_float(r.w << 16);
    acc[7] += wj * __uint_as_float(r.w & 0xffff0000u);
  }
#pragma unroll
  for (int k = 0; k < 8; k++) {
    acc[k] += __shfl_xor(acc[k], 4);
    acc[k] += __shfl_xor(acc[k], 8);
  }
  if (q == 0) {
    const float4* bias4 = (const float4*)bias;
    int bidx = h * 8 + c * 2;            // float4 index into bias
    float4 b0 = bias4[bidx], b1 = bias4[bidx + 1];
    float4 o0 = make_float4(acc[0] + b0.x, acc[1] + b0.y,
                            acc[2] + b0.z, acc[3] + b0.w);
    float4 o1 = make_float4(acc[4] + b1.x, acc[5] + b1.y,
                            acc[6] + b1.z, acc[7] + b1.w);
    size_t o = (size_t)n * 64 + h * 8 + c * 2;   // float4 index into out
    ((float4*)out)[o] = o0;
    ((float4*)out)[o + 1] = o1;
  }
}

// Fallback (fp32, full-row gather) if ws can't hold the bf16 copy.
__global__ __launch_bounds__(256) void gat_f32_kernel(
    const float4* __restrict__ featv,
    const float* __restrict__ elT,
    const float* __restrict__ erT,
    const int* __restrict__ srcIdx,
    const float* __restrict__ bias,
    float* __restrict__ out, int N) {
  int wave = threadIdx.x >> 6;
  int lane = threadIdx.x & 63;
  int n = blockIdx.x * 4 + wave;
  __shared__ float s_a[4][DEGREE][HEADS + 1];
  bool active = (n < N);
  int sidx = 0;
  if (active) {
    const int* s = srcIdx + n * DEGREE;
    int i = lane & 15;
    int hh = lane >> 4;
    sidx = s[i];
    float e0 = elT[hh * N + sidx]       + erT[hh * N + n];
    float e1 = elT[(hh + 4) * N + sidx] + erT[(hh + 4) * N + n];
    e0 = e0 > 0.0f ? e0 : NEG_SLOPE * e0;
    e1 = e1 > 0.0f ? e1 : NEG_SLOPE * e1;
    float m0 = e0, m1 = e1;
#pragma unroll
    for (int off = 8; off >= 1; off >>= 1) {
      m0 = fmaxf(m0, __shfl_xor(m0, off));
      m1 = fmaxf(m1, __shfl_xor(m1, off));
    }
    float x0 = __expf(e0 - m0), x1 = __expf(e1 - m1);
    float s0 = x0, s1 = x1;
#pragma unroll
    for (int off = 8; off >= 1; off >>= 1) {
      s0 += __shfl_xor(s0, off);
      s1 += __shfl_xor(s1, off);
    }
    s_a[wave][i][hh]     = x0 / s0;
    s_a[wave][i][hh + 4] = x1 / s1;
  }
  __syncthreads();
  if (active) {
    int h = lane >> 3;
    float4 acc = ((const float4*)bias)[lane];
#pragma unroll
    for (int j = 0; j < DEGREE; j++) {
      int sj = __shfl(sidx, j);
      float a = s_a[wave][j][h];
      float4 v = featv[(size_t)sj * 64 + lane];
      acc.x += a * v.x; acc.y += a * v.y; acc.z += a * v.z; acc.w += a * v.w;
    }
    ((float4*)out)[(size_t)n * 64 + lane] = acc;
  }
}

extern "C" void kernel_launch(void* const* d_in, const int* in_sizes, int n_in,
                              void* d_out, int out_size, void* d_ws, size_t ws_size,
                              hipStream_t stream) {
  const float* feat   = (const float*)d_in[0];
  const float* attn_l = (const float*)d_in[1];
  const float* attn_r = (const float*)d_in[2];
  const float* bias   = (const float*)d_in[3];
  const int*   src    = (const int*)d_in[4];
  // d_in[5] (dst) unused: dst == repeat(arange(N), DEG) by construction.
  float* out = (float*)d_out;

  int total = in_sizes[0];               // N * H * D
  int N = total / (HEADS * DIM);
  int total4 = total / 4;

  float* elT = (float*)d_ws;
  float* erT = elT + (size_t)N * HEADS;
  ushort4* featbH = (ushort4*)(erT + (size_t)N * HEADS);

  size_t need = (size_t)N * HEADS * 2 * sizeof(float) + (size_t)total * 2;
  bool use_bf16 = (ws_size >= need);

  if (use_bf16) {
    elr_kernel<true><<<(total4 + 255) / 256, 256, 0, stream>>>(
        (const float4*)feat, (const float4*)attn_l, (const float4*)attn_r,
        elT, erT, featbH, total4, N);
    int nchunks = (N + 15) / 16;
    gat_hmajor_kernel<<<nchunks * 8, 256, 0, stream>>>(
        (const uint4*)featbH, elT, erT, src, bias, out, N);
  } else {
    elr_kernel<false><<<(total4 + 255) / 256, 256, 0, stream>>>(
        (const float4*)feat, (const float4*)attn_l, (const float4*)attn_r,
        elT, erT, nullptr, total4, N);
    int nb = (N + 3) / 4;
    gat_f32_kernel<<<nb, 256, 0, stream>>>(
        (const float4*)feat, elT, erT, src, bias, out, N);
  }
}

// Round 6
// 161.641 us; speedup vs baseline: 1.1993x; 1.0878x over previous
//
#include <hip/hip_runtime.h>

#define HEADS 8
#define DIM 32
#define DEGREE 16
#define NEG_SLOPE 0.2f

// bf16 down-convert (RNE).
__device__ __forceinline__ unsigned short f2bf(float f) {
  unsigned u = __float_as_uint(f);
  unsigned r = (u + 0x7fffu + ((u >> 16) & 1u)) >> 16;
  return (unsigned short)r;
}

// Kernel 1: el/er dot products -> el8/er8 in [n][8] ROW-major (so one 32 B
// gather per EDGE later covers all 8 heads), plus HEAD-MAJOR bf16 feat copy
// featbH[h][n][32] (3.2 MB stripe/head -> XCD-L2-resident under blockIdx%8
// pinning; verified R5: FETCH 200->43 MB).
template <bool WRITE_BF16>
__global__ __launch_bounds__(256) void elr_kernel(
    const float4* __restrict__ feat4,
    const float4* __restrict__ attn_l4,
    const float4* __restrict__ attn_r4,
    float* __restrict__ el8, float* __restrict__ er8,
    ushort4* __restrict__ featbH, int total4, int N) {
  int t = blockIdx.x * 256 + threadIdx.x;
  if (t >= total4) return;
  float4 v = feat4[t];
  int c4 = t & 63;
  float4 al = attn_l4[c4];
  float4 ar = attn_r4[c4];
  float pl = v.x * al.x + v.y * al.y + v.z * al.z + v.w * al.w;
  float pr = v.x * ar.x + v.y * ar.y + v.z * ar.z + v.w * ar.w;
#pragma unroll
  for (int off = 4; off >= 1; off >>= 1) {
    pl += __shfl_xor(pl, off);
    pr += __shfl_xor(pr, off);
  }
  if ((t & 7) == 0) {
    el8[t >> 3] = pl;                    // t>>3 == n*8 + h
    er8[t >> 3] = pr;
  }
  if (WRITE_BF16) {
    ushort4 b;
    b.x = f2bf(v.x); b.y = f2bf(v.y); b.z = f2bf(v.z); b.w = f2bf(v.w);
    int n = t >> 6, h = c4 >> 3, d4 = c4 & 7;
    featbH[((size_t)h * N + n) * 8 + d4] = b;
  }
}

// Kernel 2 (weights): block = 16 nodes, thread = one edge (nl=t>>4, i=t&15).
// ONE 32 B gather of el8[src] per edge covers all 8 heads (0.8M requests vs
// 6.4M when each head-pinned block re-gathered logits). Softmax over the 16
// edges per head via shfl within 16-lane groups; weights stored head-major
// wH[h][n][16] with fully-coalesced 4 B stores (addr linear in t per h).
__global__ __launch_bounds__(256) void weights_kernel(
    const float4* __restrict__ el84,   // el8 as float4: row n = 2 entries
    const float4* __restrict__ er84,
    const int* __restrict__ srcIdx,
    float* __restrict__ wH, int N) {
  int t = threadIdx.x;
  int n0 = blockIdx.x * 16;
  int nl = t >> 4;
  int n = n0 + nl;
  if (n >= N) return;                    // uniform per 16-lane group
  int s = srcIdx[n0 * DEGREE + t];       // == srcIdx[n*DEGREE + (t&15)]
  float4 e0 = el84[(size_t)s * 2], e1 = el84[(size_t)s * 2 + 1];
  float4 r0 = er84[(size_t)n * 2], r1 = er84[(size_t)n * 2 + 1];
  float l[HEADS] = {e0.x + r0.x, e0.y + r0.y, e0.z + r0.z, e0.w + r0.w,
                    e1.x + r1.x, e1.y + r1.y, e1.z + r1.z, e1.w + r1.w};
  float w[HEADS];
#pragma unroll
  for (int h = 0; h < HEADS; h++) {
    float e = l[h];
    e = e > 0.0f ? e : NEG_SLOPE * e;
    float m = e;
#pragma unroll
    for (int off = 8; off >= 1; off >>= 1) m = fmaxf(m, __shfl_xor(m, off));
    float x = __expf(e - m);
    float ssum = x;
#pragma unroll
    for (int off = 8; off >= 1; off >>= 1) ssum += __shfl_xor(ssum, off);
    w[h] = x / ssum;
  }
#pragma unroll
  for (int h = 0; h < HEADS; h++)
    wH[(size_t)h * N * DEGREE + n0 * DEGREE + t] = w[h];
}

// Kernel 3 (gather-aggregate): block = 16 nodes x ONE head (h = blockIdx&7 ->
// XCD-pinned featbH stripe). No softmax, no el/er: coalesced src + weight
// loads, then the 16 feat-slice gathers per node. Lane (q=(l>>2)&3, c=l&3)
// loads 16 B chunk c of edge j=p*4+q; reduce over q via shfl_xor(4,8).
__global__ __launch_bounds__(256) void gat_kernel(
    const uint4* __restrict__ featbH4, // slice (h,n) = 4 uint4 at (h*N+n)*4
    const float* __restrict__ wH,      // [h][n][16]
    const int* __restrict__ srcIdx,
    const float* __restrict__ bias,
    float* __restrict__ out, int N) {
  int h = blockIdx.x & 7;
  int chunk = blockIdx.x >> 3;
  int t = threadIdx.x;
  int n0 = chunk * 16;
  int n = n0 + (t >> 4);
  if (n >= N) return;                    // uniform per 16-lane group
  int sidx = srcIdx[n0 * DEGREE + t];                      // coalesced
  float w = wH[(size_t)h * N * DEGREE + n0 * DEGREE + t];  // coalesced

  int lane = t & 63;
  int q = (lane >> 2) & 3;
  int c = lane & 3;
  int base = lane & 48;
  float acc[8];
#pragma unroll
  for (int k = 0; k < 8; k++) acc[k] = 0.0f;
#pragma unroll
  for (int p = 0; p < 4; p++) {
    int j = p * 4 + q;
    int sj = __shfl(sidx, base + j);
    float wj = __shfl(w, base + j);
    uint4 r = featbH4[((size_t)h * N + sj) * 4 + c];
    acc[0] += wj * __uint_as_float(r.x << 16);
    acc[1] += wj * __uint_as_float(r.x & 0xffff0000u);
    acc[2] += wj * __uint_as_float(r.y << 16);
    acc[3] += wj * __uint_as_float(r.y & 0xffff0000u);
    acc[4] += wj * __uint_as_float(r.z << 16);
    acc[5] += wj * __uint_as_float(r.z & 0xffff0000u);
    acc[6] += wj * __uint_as_float(r.w << 16);
    acc[7] += wj * __uint_as_float(r.w & 0xffff0000u);
  }
#pragma unroll
  for (int k = 0; k < 8; k++) {
    acc[k] += __shfl_xor(acc[k], 4);
    acc[k] += __shfl_xor(acc[k], 8);
  }
  if (q == 0) {
    const float4* bias4 = (const float4*)bias;
    int bidx = h * 8 + c * 2;
    float4 b0 = bias4[bidx], b1 = bias4[bidx + 1];
    float4 o0 = make_float4(acc[0] + b0.x, acc[1] + b0.y,
                            acc[2] + b0.z, acc[3] + b0.w);
    float4 o1 = make_float4(acc[4] + b1.x, acc[5] + b1.y,
                            acc[6] + b1.z, acc[7] + b1.w);
    size_t o = (size_t)n * 64 + h * 8 + c * 2;
    ((float4*)out)[o] = o0;
    ((float4*)out)[o + 1] = o1;
  }
}

// Fallback (R5-style, softmax inline, el8/er8 layout) if wH doesn't fit ws.
__global__ __launch_bounds__(256) void gat_fused_kernel(
    const uint4* __restrict__ featbH4,
    const float* __restrict__ el8,     // [n][8]
    const float* __restrict__ er8,
    const int* __restrict__ srcIdx,
    const float* __restrict__ bias,
    float* __restrict__ out, int N) {
  int h = blockIdx.x & 7;
  int chunk = blockIdx.x >> 3;
  int t = threadIdx.x;
  int n0 = chunk * 16;
  int n = n0 + (t >> 4);
  if (n >= N) return;
  int sidx = srcIdx[n0 * DEGREE + t];
  float e = el8[(size_t)sidx * 8 + h] + er8[(size_t)n * 8 + h];
  e = e > 0.0f ? e : NEG_SLOPE * e;
  float m = e;
#pragma unroll
  for (int off = 8; off >= 1; off >>= 1) m = fmaxf(m, __shfl_xor(m, off));
  float x = __expf(e - m);
  float ssum = x;
#pragma unroll
  for (int off = 8; off >= 1; off >>= 1) ssum += __shfl_xor(ssum, off);
  float w = x / ssum;

  int lane = t & 63;
  int q = (lane >> 2) & 3;
  int c = lane & 3;
  int base = lane & 48;
  float acc[8];
#pragma unroll
  for (int k = 0; k < 8; k++) acc[k] = 0.0f;
#pragma unroll
  for (int p = 0; p < 4; p++) {
    int j = p * 4 + q;
    int sj = __shfl(sidx, base + j);
    float wj = __shfl(w, base + j);
    uint4 r = featbH4[((size_t)h * N + sj) * 4 + c];
    acc[0] += wj * __uint_as_float(r.x << 16);
    acc[1] += wj * __uint_as_float(r.x & 0xffff0000u);
    acc[2] += wj * __uint_as_float(r.y << 16);
    acc[3] += wj * __uint_as_float(r.y & 0xffff0000u);
    acc[4] += wj * __uint_as_float(r.z << 16);
    acc[5] += wj * __uint_as_float(r.z & 0xffff0000u);
    acc[6] += wj * __uint_as_float(r.w << 16);
    acc[7] += wj * __uint_as_float(r.w & 0xffff0000u);
  }
#pragma unroll
  for (int k = 0; k < 8; k++) {
    acc[k] += __shfl_xor(acc[k], 4);
    acc[k] += __shfl_xor(acc[k], 8);
  }
  if (q == 0) {
    const float4* bias4 = (const float4*)bias;
    int bidx = h * 8 + c * 2;
    float4 b0 = bias4[bidx], b1 = bias4[bidx + 1];
    float4 o0 = make_float4(acc[0] + b0.x, acc[1] + b0.y,
                            acc[2] + b0.z, acc[3] + b0.w);
    float4 o1 = make_float4(acc[4] + b1.x, acc[5] + b1.y,
                            acc[6] + b1.z, acc[7] + b1.w);
    size_t o = (size_t)n * 64 + h * 8 + c * 2;
    ((float4*)out)[o] = o0;
    ((float4*)out)[o + 1] = o1;
  }
}

extern "C" void kernel_launch(void* const* d_in, const int* in_sizes, int n_in,
                              void* d_out, int out_size, void* d_ws, size_t ws_size,
                              hipStream_t stream) {
  const float* feat   = (const float*)d_in[0];
  const float* attn_l = (const float*)d_in[1];
  const float* attn_r = (const float*)d_in[2];
  const float* bias   = (const float*)d_in[3];
  const int*   src    = (const int*)d_in[4];
  // d_in[5] (dst) unused: dst == repeat(arange(N), DEG) by construction.
  float* out = (float*)d_out;

  int total = in_sizes[0];               // N * H * D
  int N = total / (HEADS * DIM);
  int total4 = total / 4;
  int nchunks = (N + 15) / 16;

  float* el8 = (float*)d_ws;                                  // N*8 fp32
  float* er8 = el8 + (size_t)N * HEADS;                       // N*8 fp32
  ushort4* featbH = (ushort4*)(er8 + (size_t)N * HEADS);      // N*256 bf16
  float* wH = (float*)(featbH + (size_t)total / 4);           // N*16*8 fp32

  size_t need_base = (size_t)N * HEADS * 2 * sizeof(float);
  size_t need_feat = need_base + (size_t)total * 2;
  size_t need_full = need_feat + (size_t)N * DEGREE * HEADS * sizeof(float);

  if (ws_size >= need_full) {
    elr_kernel<true><<<(total4 + 255) / 256, 256, 0, stream>>>(
        (const float4*)feat, (const float4*)attn_l, (const float4*)attn_r,
        el8, er8, featbH, total4, N);
    weights_kernel<<<nchunks, 256, 0, stream>>>(
        (const float4*)el8, (const float4*)er8, src, wH, N);
    gat_kernel<<<nchunks * 8, 256, 0, stream>>>(
        (const uint4*)featbH, wH, src, bias, out, N);
  } else {
    elr_kernel<true><<<(total4 + 255) / 256, 256, 0, stream>>>(
        (const float4*)feat, (const float4*)attn_l, (const float4*)attn_r,
        el8, er8, featbH, total4, N);
    gat_fused_kernel<<<nchunks * 8, 256, 0, stream>>>(
        (const uint4*)featbH, el8, er8, src, bias, out, N);
  }
}